// Round 4
// baseline (436.378 us; speedup 1.0000x reference)
//
#include <hip/hip_runtime.h>

// LSTM: B=4096, T=2048, I=4, H=3, gates i,f,g,o (W rows r = g*3 + u)
// R4: 16 lanes per sequence (quad q = unit, q==3 dup; lane-in-quad s = gate).
//     Cross-quad h gather via DPP row_ror (runtime direction probe) instead of
//     ds_swizzle -- removes lgkmcnt wait from the recurrence chain.
//     c' = 2*log2e*c maintained to kill one mul on the tanh chain.

#define BB 4096
#define TT 2048
#define L2E 1.4426950408889634f

template<int CTRL>
__device__ __forceinline__ int dpp_i(int v) {
    return __builtin_amdgcn_update_dpp(0, v, CTRL, 0xF, 0xF, true);
}
template<int CTRL>
__device__ __forceinline__ float dpp_f(float v) {
    return __int_as_float(dpp_i<CTRL>(__float_as_int(v)));
}
#define ROR4  0x124
#define ROR8  0x128
#define ROR12 0x12C

__global__ __launch_bounds__(64, 1) void lstm_seq(
    const float* __restrict__ x, const float* __restrict__ Wih,
    const float* __restrict__ Whh, const float* __restrict__ bih,
    const float* __restrict__ bhh, const int* __restrict__ len,
    float* __restrict__ out)
{
    const int lane  = threadIdx.x & 63;
    const int s     = lane & 3;          // gate: 0=i,1=f,2=g,3=o
    const int q     = (lane >> 2) & 3;   // quad = unit (3 = dup of unit 2)
    const int row16 = lane >> 4;         // sequence within wave (4 per wave)
    const int b     = blockIdx.x * 4 + row16;
    const int u     = (q < 3) ? q : 2;
    const int wrow  = s * 3 + u;

    // r = rcp(1+exp2(a)) with pre-scaled a:
    //   sigmoid (s!=2): scale=-log2e,  act = r            (Aa=0, Bb=1)
    //   tanhx2L (s==2): scale=+2log2e, act = 2L - 4L*r    (= 2*log2e*tanh)
    const float scale = (s == 2) ? (2.f * L2E) : (-L2E);
    const float Aa = (s == 2) ? (2.f * L2E) : 0.f;
    const float Bb = (s == 2) ? (-4.f * L2E) : 1.f;

    const float xw0 = Wih[wrow * 4 + 0] * scale;
    const float xw1 = Wih[wrow * 4 + 1] * scale;
    const float xw2 = Wih[wrow * 4 + 2] * scale;
    const float xw3 = Wih[wrow * 4 + 3] * scale;
    const float bias = (bih[wrow] + bhh[wrow]) * scale;

    // Runtime probe: which quad's value arrives in each ror slot?
    const int p1 = (dpp_i<ROR4 >(lane) >> 2) & 3;
    const int p2 = (dpp_i<ROR8 >(lane) >> 2) & 3;
    const int p3 = (dpp_i<ROR12>(lane) >> 2) & 3;
    const int srcq[4] = {q, p1, p2, p3};
    float wh[4];
    #pragma unroll
    for (int j = 0; j < 4; ++j)
        wh[j] = (srcq[j] == 3) ? 0.f : Whh[wrow * 3 + srcq[j]] * scale;

    const int mylen = len[b];
    int wmax = mylen;
    #pragma unroll
    for (int off = 1; off < 64; off <<= 1)
        wmax = max(wmax, __shfl_xor(wmax, off));
    const int Tloop = (wmax + 7) & ~7;

    float hs0 = 0.f, hs1 = 0.f, hs2 = 0.f, hs3 = 0.f, cp = 0.f; // cp = 2L*c
    const float4* __restrict__ xrow = ((const float4*)x) + (size_t)b * TT;
    float* __restrict__ orow = out + (size_t)b * (TT * 3);
    const bool writer = (s == 0) && (q < 3);

    float4 buf[8];
    float xacc[8];
    #pragma unroll
    for (int uu = 0; uu < 8; ++uu) buf[uu] = xrow[uu];

    for (int tb = 0; tb < Tloop; tb += 8) {
        #pragma unroll
        for (int uu = 0; uu < 8; ++uu) {
            const float4 xv = buf[uu];
            xacc[uu] = fmaf(xw3, xv.w, fmaf(xw2, xv.z,
                       fmaf(xw1, xv.y, fmaf(xw0, xv.x, bias))));
        }
        #pragma unroll
        for (int uu = 0; uu < 8; ++uu) {
            const int tn = tb + 8 + uu;
            buf[uu] = xrow[tn < TT ? tn : 0];
        }
        #pragma unroll
        for (int uu = 0; uu < 8; ++uu) {
            const int t = tb + uu;
            // balanced dot: depth 12 from h-arrival
            const float t0 = fmaf(wh[1], hs1, fmaf(wh[0], hs0, xacc[uu]));
            const float t1 = fmaf(wh[3], hs3, wh[2] * hs2);
            const float a  = t0 + t1;
            const float r   = __builtin_amdgcn_rcpf(1.f + __builtin_amdgcn_exp2f(a));
            const float act = fmaf(Bb, r, Aa);
            const float gi = dpp_f<0x00>(act);   // gate i (sigmoid)
            const float gf = dpp_f<0x55>(act);   // gate f (sigmoid)
            const float gg = dpp_f<0xAA>(act);   // gate g (2L*tanh)
            const float go = dpp_f<0xFF>(act);   // gate o (sigmoid)
            cp = fmaf(gf, cp, gi * gg);          // cp = 2L * c
            const float tc = fmaf(-2.f,
                __builtin_amdgcn_rcpf(1.f + __builtin_amdgcn_exp2f(cp)), 1.f);
            const float myh = go * tc;
            hs0 = myh;
            hs1 = dpp_f<ROR4 >(myh);
            hs2 = dpp_f<ROR8 >(myh);
            hs3 = dpp_f<ROR12>(myh);
            if (writer) orow[t * 3 + q] = (t < mylen) ? myh : 0.f;
        }
    }

    // Zero the remaining tail t in [Tloop, TT) for this wave's 4 rows.
    const int start4 = Tloop * 3 / 4;          // multiple of 6, 16B-aligned
    #pragma unroll
    for (int rr = 0; rr < 4; ++rr) {
        float4* __restrict__ o4 = (float4*)(out + ((size_t)(blockIdx.x * 4 + rr)) * (TT * 3));
        for (int idx = start4 + lane; idx < TT * 3 / 4; idx += 64)
            o4[idx] = make_float4(0.f, 0.f, 0.f, 0.f);
    }
}

extern "C" void kernel_launch(void* const* d_in, const int* in_sizes, int n_in,
                              void* d_out, int out_size, void* d_ws, size_t ws_size,
                              hipStream_t stream) {
    const float* x    = (const float*)d_in[0];
    const float* Wih  = (const float*)d_in[1];
    const float* Whh  = (const float*)d_in[2];
    const float* bih  = (const float*)d_in[3];
    const float* bhh  = (const float*)d_in[4];
    const int*   lenp = (const int*)d_in[5];
    float* out = (float*)d_out;

    lstm_seq<<<BB / 4, 64, 0, stream>>>(x, Wih, Whh, bih, bhh, lenp, out);
}